// Round 6
// baseline (4687.611 us; speedup 1.0000x reference)
//
#include <hip/hip_runtime.h>
#include <hip/hip_bf16.h>
#include <math.h>

#define SLEN 2048
#define DDIM 512
#define BNUM 8
#define MTOT (BNUM * SLEN)   // 16384

typedef float f32x4 __attribute__((ext_vector_type(4)));

// ---------------------------------------------------------------------------
// Agent-scope (device-coherent) 8-byte access helpers. `sc1` bypasses the
// non-coherent per-XCD caches; coherence point = device LLC. ALL writers and
// readers of the tag buffer use exactly this path (round-3 lesson: a single
// coherence point, including the clearing kernel).
// ---------------------------------------------------------------------------
__device__ __forceinline__ uint2 ld_u64_agent(const uint2* p) {
    uint2 v;
    asm volatile("global_load_dwordx2 %0, %1, off sc1\n\ts_waitcnt vmcnt(0)"
                 : "=v"(v) : "v"(p) : "memory");
    return v;
}
__device__ __forceinline__ void st_u64_agent(uint2* p, uint2 v) {
    asm volatile("global_store_dwordx2 %0, %1, off sc1"
                 :: "v"(p), "v"(v) : "memory");
}

// ---------------------------------------------------------------------------
// Kernel 0: clear tag buffer through the SAME sc1 path the scan uses.
// ---------------------------------------------------------------------------
__global__ __launch_bounds__(512) void clear_tags_kernel(uint2* stateTag)
{
    int i = blockIdx.x * 512 + threadIdx.x;
    uint2 z; z.x = 0u; z.y = 0u;
    st_u64_agent(&stateTag[i], z);
}

// ---------------------------------------------------------------------------
// Kernel A: fused precompute GEMM  O = act(x @ [Wu|Wa|Wc|Wg]^T + bias)
// ---------------------------------------------------------------------------
__global__ __launch_bounds__(256) void precompute_kernel(
    const float* __restrict__ x,
    const float* __restrict__ Wu, const float* __restrict__ bu,
    const float* __restrict__ Wa, const float* __restrict__ ba,
    const float* __restrict__ Wc, const float* __restrict__ bc,
    const float* __restrict__ Wg, const float* __restrict__ bg,
    float* __restrict__ gbuf, float* __restrict__ cosb,
    float* __restrict__ sinb, float* __restrict__ cdbuf,
    float* __restrict__ ogout)
{
    __shared__ float As[8][132];
    __shared__ float Bs[8][132];

    const int bn = blockIdx.x * 128;      // 0..1791 in steps of 128
    const int bm = blockIdx.y * 128;      // 0..16383

    const float* W; const float* bias; int mode; int dcol;
    if (bn < 512)       { W = Wu; bias = bu; mode = 0; dcol = bn; }
    else if (bn < 768)  { W = Wa; bias = ba; mode = 1; dcol = bn - 512; }
    else if (bn < 1280) { W = Wc; bias = bc; mode = 2; dcol = bn - 768; }
    else                { W = Wg; bias = bg; mode = 3; dcol = bn - 1280; }

    const int tid = threadIdx.x;
    const int tx = tid & 15, ty = tid >> 4;

    float acc[8][8];
    #pragma unroll
    for (int i = 0; i < 8; ++i)
        #pragma unroll
        for (int j = 0; j < 8; ++j) acc[i][j] = 0.f;

    for (int k0 = 0; k0 < DDIM; k0 += 8) {
        #pragma unroll
        for (int l = 0; l < 4; ++l) {
            int idx = l * 256 + tid;
            int kk = idx & 7, mm = idx >> 3;
            As[kk][mm] = x[(size_t)(bm + mm) * DDIM + k0 + kk];
            Bs[kk][mm] = W[(size_t)(dcol + mm) * DDIM + k0 + kk];
        }
        __syncthreads();
        #pragma unroll
        for (int kk = 0; kk < 8; ++kk) {
            float av[8], bv[8];
            *(float4*)&av[0] = *(const float4*)&As[kk][ty * 8];
            *(float4*)&av[4] = *(const float4*)&As[kk][ty * 8 + 4];
            *(float4*)&bv[0] = *(const float4*)&Bs[kk][tx * 8];
            *(float4*)&bv[4] = *(const float4*)&Bs[kk][tx * 8 + 4];
            #pragma unroll
            for (int i = 0; i < 8; ++i)
                #pragma unroll
                for (int j = 0; j < 8; ++j)
                    acc[i][j] = fmaf(av[i], bv[j], acc[i][j]);
        }
        __syncthreads();
    }

    #pragma unroll
    for (int i = 0; i < 8; ++i) {
        int m = bm + ty * 8 + i;
        #pragma unroll
        for (int j = 0; j < 8; ++j) {
            int n = dcol + tx * 8 + j;
            float v = acc[i][j] + bias[n];
            if (mode == 0) {
                gbuf[(size_t)m * 512 + n] = 1.f / (1.f + expf(-v));
            } else if (mode == 1) {
                cosb[(size_t)m * 256 + n] = cosf(v);
                sinb[(size_t)m * 256 + n] = sinf(v);
            } else if (mode == 2) {
                cdbuf[(size_t)m * 512 + n] = tanhf(v);
            } else {
                ogout[(size_t)m * 512 + n] = 1.f / (1.f + expf(-v));
            }
        }
    }
}

// ---------------------------------------------------------------------------
// Kernel B: sequential scan. 32 persistent WGs of 1024 threads: batch
// b = wg&7, quarter q = wg>>3 owns output rows [q*128, q*128+128).
// Per thread: row r = tid>>3, kpart = tid&7 -> 64 fp32 weights in 16 named
// f32x4 variables, PINNED to VGPRs via an empty volatile asm (the values'
// origin becomes the asm, so the compiler cannot rematerialize the loads —
// round-5 showed VGPR_Count=60 < 64: weights were being re-streamed from L2
// every step, ~256KB/WG/step, the dominant cost).
// LDS state padded [8][68] -> conflict-free broadcast reads.
// Gates for step s+1 prefetched during step s. Cross-WG exchange:
// generation-tagged double buffer via sc1 (rounds 4-5 proven protocol).
// ---------------------------------------------------------------------------
__global__ __launch_bounds__(1024, 4) void scan_kernel(
    const float* __restrict__ Wt, const float* __restrict__ bt,
    const float* __restrict__ gbuf, const float* __restrict__ cosb,
    const float* __restrict__ sinb, const float* __restrict__ cdbuf,
    float* __restrict__ states, uint2* stateTag,
    float* __restrict__ finalOut)
{
    const int wg = blockIdx.x;
    const int b = wg & 7, q = wg >> 3;
    const int tid = threadIdx.x;
    const int r = tid >> 3;          // 0..127 local output row
    const int kpart = tid & 7;       // 0..7
    const int o = q * 128 + r;       // global output dim
    const int kbase = kpart * 64;

    // Register-resident weight slice: Wt[o][kbase .. kbase+64)
    const float* wrow = Wt + (size_t)o * DDIM + kbase;
    f32x4 w0  = *(const f32x4*)(wrow +  0);
    f32x4 w1  = *(const f32x4*)(wrow +  4);
    f32x4 w2  = *(const f32x4*)(wrow +  8);
    f32x4 w3  = *(const f32x4*)(wrow + 12);
    f32x4 w4  = *(const f32x4*)(wrow + 16);
    f32x4 w5  = *(const f32x4*)(wrow + 20);
    f32x4 w6  = *(const f32x4*)(wrow + 24);
    f32x4 w7  = *(const f32x4*)(wrow + 28);
    f32x4 w8  = *(const f32x4*)(wrow + 32);
    f32x4 w9  = *(const f32x4*)(wrow + 36);
    f32x4 w10 = *(const f32x4*)(wrow + 40);
    f32x4 w11 = *(const f32x4*)(wrow + 44);
    f32x4 w12 = *(const f32x4*)(wrow + 48);
    f32x4 w13 = *(const f32x4*)(wrow + 52);
    f32x4 w14 = *(const f32x4*)(wrow + 56);
    f32x4 w15 = *(const f32x4*)(wrow + 60);
    // Pin: values now originate from a volatile asm -> no rematerialization.
    asm volatile("" : "+v"(w0), "+v"(w1), "+v"(w2),  "+v"(w3),
                      "+v"(w4), "+v"(w5), "+v"(w6),  "+v"(w7),
                      "+v"(w8), "+v"(w9), "+v"(w10), "+v"(w11),
                      "+v"(w12), "+v"(w13), "+v"(w14), "+v"(w15));

    const float btv = (kpart == 0) ? bt[o] : 0.f;

    __shared__ float lds8[8][68];    // padded: segment p at row p
    __shared__ float t_vals[128];

    const float* pg  = gbuf + (size_t)b * SLEN * 512;
    const float* pcd = cdbuf + (size_t)b * SLEN * 512;
    const float* pc  = cosb + (size_t)b * SLEN * 256;
    const float* psn = sinb + (size_t)b * SLEN * 256;
    float* stb = states + (size_t)b * SLEN * 512;

    // gate double-buffer registers; prologue loads step 0
    float gN = 0.f, cdN = 0.f, cN = 0.f, snN = 0.f;
    if (tid < 128) {
        int oo = q * 128 + tid;
        gN  = pg [(size_t)0 * 512 + oo];
        cdN = pcd[(size_t)0 * 512 + oo];
        cN  = pc [(size_t)0 * 256 + (oo >> 1)];
        snN = psn[(size_t)0 * 256 + (oo >> 1)];
    }

    for (int s = 0; s < SLEN; ++s) {
        float gC = gN, cdC = cdN, cC = cN, snC = snN;

        // ---- obtain S_s into LDS (padded layout) ----
        if (s == 0) {
            if (tid < 512) lds8[tid >> 6][tid & 63] = 0.f;
        } else {
            if (tid < 512 && (tid >> 7) != q) {   // own quarter already fresh
                const uint2* p = stateTag +
                    ((size_t)(s & 1) * BNUM + b) * 512 + tid;
                uint2 u; int guard = 0;
                do { u = ld_u64_agent(p); }
                while (u.y != (unsigned)s && ++guard < (1 << 16));
                lds8[tid >> 6][tid & 63] = __uint_as_float(u.x);
            }
        }
        __syncthreads();

        // ---- prefetch NEXT step's gates (overlaps matvec etc.) ----
        if (tid < 128) {
            int sp1 = (s + 1) & (SLEN - 1);       // wrap harmlessly at end
            int oo = q * 128 + tid;
            gN  = pg [(size_t)sp1 * 512 + oo];
            cdN = pcd[(size_t)sp1 * 512 + oo];
            cN  = pc [(size_t)sp1 * 256 + (oo >> 1)];
            snN = psn[(size_t)sp1 * 256 + (oo >> 1)];
        }

        // ---- matvec t = Wt[o,:] . S_s (64 MACs/thread, weights in VGPR) ----
        float p0 = 0.f, p1 = 0.f, p2 = 0.f, p3 = 0.f;
        const float* st = &lds8[kpart][0];
        {
            f32x4 sv;
            #define MACV(WV, OFF) \
                sv = *(const f32x4*)(st + OFF); \
                p0 = fmaf(WV.x, sv.x, p0); \
                p1 = fmaf(WV.y, sv.y, p1); \
                p2 = fmaf(WV.z, sv.z, p2); \
                p3 = fmaf(WV.w, sv.w, p3);
            MACV(w0,  0)  MACV(w1,  4)  MACV(w2,  8)  MACV(w3,  12)
            MACV(w4,  16) MACV(w5,  20) MACV(w6,  24) MACV(w7,  28)
            MACV(w8,  32) MACV(w9,  36) MACV(w10, 40) MACV(w11, 44)
            MACV(w12, 48) MACV(w13, 52) MACV(w14, 56) MACV(w15, 60)
            #undef MACV
        }
        float partial = (p0 + p1) + (p2 + p3);
        partial += __shfl_xor(partial, 1);
        partial += __shfl_xor(partial, 2);
        partial += __shfl_xor(partial, 4);
        if (kpart == 0) t_vals[r] = partial + btv;
        __syncthreads();

        // ---- rotate, gate, publish S_{s+1} (publish store FIRST) ----
        if (tid < 128) {
            int oo = q * 128 + tid;
            float tv = t_vals[tid];
            float tp = t_vals[tid ^ 1];
            float rot = (tid & 1) ? fmaf(tp, snC, tv * cC)
                                  : fmaf(tv, cC, -(tp * snC));
            float nxt = fmaf(gC, rot, (1.f - gC) * cdC);
            uint2 u; u.x = __float_as_uint(nxt); u.y = (unsigned)(s + 1);
            st_u64_agent(&stateTag[((size_t)((s + 1) & 1) * BNUM + b) * 512 + oo], u);
            stb[(size_t)s * 512 + oo] = nxt;              // for emit kernel
            int e = oo;                                   // own-quarter LDS update
            lds8[e >> 6][e & 63] = nxt;
            if (s == SLEN - 1) finalOut[b * 512 + oo] = nxt;
        }
        // No barrier needed: next iteration's fill writes only non-own
        // segments (disjoint), and all step-s LDS reads completed before
        // the t_vals barrier.
    }
}

// ---------------------------------------------------------------------------
// Kernel C: emitted = og * (states @ Wo^T + bo). og staged in d_out by A.
// ---------------------------------------------------------------------------
__global__ __launch_bounds__(256) void emit_kernel(
    const float* __restrict__ states, const float* __restrict__ Wo,
    const float* __restrict__ bo, float* __restrict__ out)
{
    __shared__ float As[8][132];
    __shared__ float Bs[8][132];

    const int bn = blockIdx.x * 128;
    const int bm = blockIdx.y * 128;
    const int tid = threadIdx.x;
    const int tx = tid & 15, ty = tid >> 4;

    float acc[8][8];
    #pragma unroll
    for (int i = 0; i < 8; ++i)
        #pragma unroll
        for (int j = 0; j < 8; ++j) acc[i][j] = 0.f;

    for (int k0 = 0; k0 < DDIM; k0 += 8) {
        #pragma unroll
        for (int l = 0; l < 4; ++l) {
            int idx = l * 256 + tid;
            int kk = idx & 7, mm = idx >> 3;
            As[kk][mm] = states[(size_t)(bm + mm) * DDIM + k0 + kk];
            Bs[kk][mm] = Wo[(size_t)(bn + mm) * DDIM + k0 + kk];
        }
        __syncthreads();
        #pragma unroll
        for (int kk = 0; kk < 8; ++kk) {
            float av[8], bv[8];
            *(float4*)&av[0] = *(const float4*)&As[kk][ty * 8];
            *(float4*)&av[4] = *(const float4*)&As[kk][ty * 8 + 4];
            *(float4*)&bv[0] = *(const float4*)&Bs[kk][tx * 8];
            *(float4*)&bv[4] = *(const float4*)&Bs[kk][tx * 8 + 4];
            #pragma unroll
            for (int i = 0; i < 8; ++i)
                #pragma unroll
                for (int j = 0; j < 8; ++j)
                    acc[i][j] = fmaf(av[i], bv[j], acc[i][j]);
        }
        __syncthreads();
    }

    #pragma unroll
    for (int i = 0; i < 8; ++i) {
        int m = bm + ty * 8 + i;
        #pragma unroll
        for (int j = 0; j < 8; ++j) {
            int n = bn + tx * 8 + j;
            size_t idx = (size_t)m * 512 + n;
            float og = out[idx];
            out[idx] = og * (acc[i][j] + bo[n]);
        }
    }
}

// ---------------------------------------------------------------------------
extern "C" void kernel_launch(void* const* d_in, const int* in_sizes, int n_in,
                              void* d_out, int out_size, void* d_ws, size_t ws_size,
                              hipStream_t stream)
{
    const float* x  = (const float*)d_in[0];
    const float* Wu = (const float*)d_in[1];
    const float* bu = (const float*)d_in[2];
    const float* Wt = (const float*)d_in[3];
    const float* bt = (const float*)d_in[4];
    const float* Wa = (const float*)d_in[5];
    const float* ba = (const float*)d_in[6];
    const float* Wc = (const float*)d_in[7];
    const float* bc = (const float*)d_in[8];
    const float* Wg = (const float*)d_in[9];
    const float* bg = (const float*)d_in[10];
    const float* Wo = (const float*)d_in[11];
    const float* bo = (const float*)d_in[12];
    float* out = (float*)d_out;

    // workspace layout (floats)
    float* wsf    = (float*)d_ws;
    float* gbuf   = wsf;                               // 16384*512
    float* cosb   = gbuf   + (size_t)MTOT * 512;       // 16384*256
    float* sinb   = cosb   + (size_t)MTOT * 256;       // 16384*256
    float* cdbuf  = sinb   + (size_t)MTOT * 256;       // 16384*512
    float* states = cdbuf  + (size_t)MTOT * 512;       // 16384*512
    uint2* stateTag = (uint2*)(states + (size_t)MTOT * 512); // 2*8*512 uint2

    // clear tags through the sc1 path (same path the scan uses).
    clear_tags_kernel<<<16, 512, 0, stream>>>(stateTag);

    precompute_kernel<<<dim3(14, 128), 256, 0, stream>>>(
        x, Wu, bu, Wa, ba, Wc, bc, Wg, bg,
        gbuf, cosb, sinb, cdbuf, out /* og staged in emitted region */);

    scan_kernel<<<32, 1024, 0, stream>>>(
        Wt, bt, gbuf, cosb, sinb, cdbuf,
        states, stateTag, out + (size_t)MTOT * 512);

    emit_kernel<<<dim3(4, 128), 256, 0, stream>>>(states, Wo, bo, out);
}

// Round 7
// 4283.743 us; speedup vs baseline: 1.0943x; 1.0943x over previous
//
#include <hip/hip_runtime.h>
#include <hip/hip_bf16.h>
#include <math.h>

#define SLEN 2048
#define DDIM 512
#define BNUM 8
#define MTOT (BNUM * SLEN)   // 16384

typedef float f32x4 __attribute__((ext_vector_type(4)));

// ---------------------------------------------------------------------------
// Agent-scope (device-coherent) 8-byte access helpers. `sc1` bypasses the
// non-coherent per-XCD caches; coherence point = device LLC. ALL writers and
// readers of the tag buffer use exactly this path (round-3 lesson: single
// coherence point, including the clearing kernel).
// ---------------------------------------------------------------------------
__device__ __forceinline__ uint2 ld_u64_agent(const uint2* p) {
    uint2 v;
    asm volatile("global_load_dwordx2 %0, %1, off sc1\n\ts_waitcnt vmcnt(0)"
                 : "=v"(v) : "v"(p) : "memory");
    return v;
}
__device__ __forceinline__ void st_u64_agent(uint2* p, uint2 v) {
    asm volatile("global_store_dwordx2 %0, %1, off sc1"
                 :: "v"(p), "v"(v) : "memory");
}

// ---------------------------------------------------------------------------
// Kernel 0: clear tag buffer through the SAME sc1 path the scan uses.
// ---------------------------------------------------------------------------
__global__ __launch_bounds__(512) void clear_tags_kernel(uint2* stateTag)
{
    int i = blockIdx.x * 512 + threadIdx.x;
    uint2 z; z.x = 0u; z.y = 0u;
    st_u64_agent(&stateTag[i], z);
}

// ---------------------------------------------------------------------------
// Kernel A: fused precompute GEMM  O = act(x @ [Wu|Wa|Wc|Wg]^T + bias)
// ---------------------------------------------------------------------------
__global__ __launch_bounds__(256) void precompute_kernel(
    const float* __restrict__ x,
    const float* __restrict__ Wu, const float* __restrict__ bu,
    const float* __restrict__ Wa, const float* __restrict__ ba,
    const float* __restrict__ Wc, const float* __restrict__ bc,
    const float* __restrict__ Wg, const float* __restrict__ bg,
    float* __restrict__ gbuf, float* __restrict__ cosb,
    float* __restrict__ sinb, float* __restrict__ cdbuf,
    float* __restrict__ ogout)
{
    __shared__ float As[8][132];
    __shared__ float Bs[8][132];

    const int bn = blockIdx.x * 128;      // 0..1791 in steps of 128
    const int bm = blockIdx.y * 128;      // 0..16383

    const float* W; const float* bias; int mode; int dcol;
    if (bn < 512)       { W = Wu; bias = bu; mode = 0; dcol = bn; }
    else if (bn < 768)  { W = Wa; bias = ba; mode = 1; dcol = bn - 512; }
    else if (bn < 1280) { W = Wc; bias = bc; mode = 2; dcol = bn - 768; }
    else                { W = Wg; bias = bg; mode = 3; dcol = bn - 1280; }

    const int tid = threadIdx.x;
    const int tx = tid & 15, ty = tid >> 4;

    float acc[8][8];
    #pragma unroll
    for (int i = 0; i < 8; ++i)
        #pragma unroll
        for (int j = 0; j < 8; ++j) acc[i][j] = 0.f;

    for (int k0 = 0; k0 < DDIM; k0 += 8) {
        #pragma unroll
        for (int l = 0; l < 4; ++l) {
            int idx = l * 256 + tid;
            int kk = idx & 7, mm = idx >> 3;
            As[kk][mm] = x[(size_t)(bm + mm) * DDIM + k0 + kk];
            Bs[kk][mm] = W[(size_t)(dcol + mm) * DDIM + k0 + kk];
        }
        __syncthreads();
        #pragma unroll
        for (int kk = 0; kk < 8; ++kk) {
            float av[8], bv[8];
            *(float4*)&av[0] = *(const float4*)&As[kk][ty * 8];
            *(float4*)&av[4] = *(const float4*)&As[kk][ty * 8 + 4];
            *(float4*)&bv[0] = *(const float4*)&Bs[kk][tx * 8];
            *(float4*)&bv[4] = *(const float4*)&Bs[kk][tx * 8 + 4];
            #pragma unroll
            for (int i = 0; i < 8; ++i)
                #pragma unroll
                for (int j = 0; j < 8; ++j)
                    acc[i][j] = fmaf(av[i], bv[j], acc[i][j]);
        }
        __syncthreads();
    }

    #pragma unroll
    for (int i = 0; i < 8; ++i) {
        int m = bm + ty * 8 + i;
        #pragma unroll
        for (int j = 0; j < 8; ++j) {
            int n = dcol + tx * 8 + j;
            float v = acc[i][j] + bias[n];
            if (mode == 0) {
                gbuf[(size_t)m * 512 + n] = 1.f / (1.f + expf(-v));
            } else if (mode == 1) {
                cosb[(size_t)m * 256 + n] = cosf(v);
                sinb[(size_t)m * 256 + n] = sinf(v);
            } else if (mode == 2) {
                cdbuf[(size_t)m * 512 + n] = tanhf(v);
            } else {
                ogout[(size_t)m * 512 + n] = 1.f / (1.f + expf(-v));
            }
        }
    }
}

// ---------------------------------------------------------------------------
// Kernel B: sequential scan. 64 persistent WGs of 512 threads: batch
// b = wg&7, octant oct = wg>>3 owns output rows [oct*64, oct*64+64).
// Per thread: row r = tid>>3, kpart = tid&7 -> 64 fp32 weights in 16 named
// f32x4 VGPR vars (pinned). 512-thr WG = 8 waves = 2 waves/SIMD, and
// __launch_bounds__(512,2) -> ~256-VGPR budget: weights truly resident
// (round 5/6: 1024-thr WG forced a ~64-VGPR budget -> weights re-streamed
// from L2 every step, the dominant cost).
// Role split BY WAVE: lane tid owns state element e=tid. Own elements
// (e>>6==oct) = wave `oct` exactly -> that wave does rotate/gate/publish/
// states-store (all stores). Other 7 waves only poll+fill LDS, so their
// per-wave vmcnt(0) waits ONLY on their own 8B LLC poll load — no store
// acks or gate prefetches in their queue.
// Cross-WG exchange: generation-tagged double buffer via sc1 (rounds 4-6
// proven protocol, unchanged).
// ---------------------------------------------------------------------------
__global__ __launch_bounds__(512, 2) void scan_kernel(
    const float* __restrict__ Wt, const float* __restrict__ bt,
    const float* __restrict__ gbuf, const float* __restrict__ cosb,
    const float* __restrict__ sinb, const float* __restrict__ cdbuf,
    float* __restrict__ states, uint2* stateTag,
    float* __restrict__ finalOut)
{
    const int wg = blockIdx.x;
    const int b = wg & 7, oct = wg >> 3;
    const int tid = threadIdx.x;
    const int r = tid >> 3;          // 0..63 local output row
    const int kpart = tid & 7;       // 0..7
    const int o = oct * 64 + r;      // global output row
    const int e = tid;               // state element this lane fills/publishes
    const bool isPub = ((tid >> 6) == oct);   // wave `oct`

    // Register-resident weight slice: Wt[o][kpart*64 .. kpart*64+64)
    const float* wrow = Wt + (size_t)o * DDIM + kpart * 64;
    f32x4 w0  = *(const f32x4*)(wrow +  0);
    f32x4 w1  = *(const f32x4*)(wrow +  4);
    f32x4 w2  = *(const f32x4*)(wrow +  8);
    f32x4 w3  = *(const f32x4*)(wrow + 12);
    f32x4 w4  = *(const f32x4*)(wrow + 16);
    f32x4 w5  = *(const f32x4*)(wrow + 20);
    f32x4 w6  = *(const f32x4*)(wrow + 24);
    f32x4 w7  = *(const f32x4*)(wrow + 28);
    f32x4 w8  = *(const f32x4*)(wrow + 32);
    f32x4 w9  = *(const f32x4*)(wrow + 36);
    f32x4 w10 = *(const f32x4*)(wrow + 40);
    f32x4 w11 = *(const f32x4*)(wrow + 44);
    f32x4 w12 = *(const f32x4*)(wrow + 48);
    f32x4 w13 = *(const f32x4*)(wrow + 52);
    f32x4 w14 = *(const f32x4*)(wrow + 56);
    f32x4 w15 = *(const f32x4*)(wrow + 60);
    asm volatile("" : "+v"(w0), "+v"(w1), "+v"(w2),  "+v"(w3),
                      "+v"(w4), "+v"(w5), "+v"(w6),  "+v"(w7),
                      "+v"(w8), "+v"(w9), "+v"(w10), "+v"(w11),
                      "+v"(w12), "+v"(w13), "+v"(w14), "+v"(w15));

    const float btv = (kpart == 0) ? bt[o] : 0.f;

    __shared__ float lds8[8][68];    // padded: segment p starts at bank 4p%32
    __shared__ float t_vals[64];

    const float* pg  = gbuf + (size_t)b * SLEN * 512;
    const float* pcd = cdbuf + (size_t)b * SLEN * 512;
    const float* pc  = cosb + (size_t)b * SLEN * 256;
    const float* psn = sinb + (size_t)b * SLEN * 256;
    float* stb = states + (size_t)b * SLEN * 512;

    // init S_0 = 0 (every lane writes its element)
    lds8[e >> 6][e & 63] = 0.f;

    // gate prologue (publisher wave only; one element per lane)
    float gN = 0.f, cdN = 0.f, cN = 0.f, snN = 0.f;
    if (isPub) {
        gN  = pg [e];
        cdN = pcd[e];
        cN  = pc [e >> 1];
        snN = psn[e >> 1];
    }

    for (int s = 0; s < SLEN; ++s) {
        __syncthreads();   // barrier1: lds8 holds S_s

        // ---- matvec t = Wt[o,:] . S_s (64 MACs/thread, weights in VGPR) ----
        float p0 = 0.f, p1 = 0.f, p2 = 0.f, p3 = 0.f;
        const float* st = &lds8[kpart][0];
        {
            f32x4 sv;
            #define MACV(WV, OFF) \
                sv = *(const f32x4*)(st + OFF); \
                p0 = fmaf(WV.x, sv.x, p0); \
                p1 = fmaf(WV.y, sv.y, p1); \
                p2 = fmaf(WV.z, sv.z, p2); \
                p3 = fmaf(WV.w, sv.w, p3);
            MACV(w0,  0)  MACV(w1,  4)  MACV(w2,  8)  MACV(w3,  12)
            MACV(w4,  16) MACV(w5,  20) MACV(w6,  24) MACV(w7,  28)
            MACV(w8,  32) MACV(w9,  36) MACV(w10, 40) MACV(w11, 44)
            MACV(w12, 48) MACV(w13, 52) MACV(w14, 56) MACV(w15, 60)
            #undef MACV
        }
        float partial = (p0 + p1) + (p2 + p3);
        partial += __shfl_xor(partial, 1);
        partial += __shfl_xor(partial, 2);
        partial += __shfl_xor(partial, 4);
        if (kpart == 0) t_vals[r] = partial + btv;
        __syncthreads();   // barrier2: t_vals ready

        if (isPub) {
            // ---- rotate, gate, publish S_{s+1}[e] (tag store FIRST) ----
            int lr = e & 63;
            float tv = t_vals[lr];
            float tp = t_vals[lr ^ 1];
            float rot = (e & 1) ? fmaf(tp, snN, tv * cN)
                                : fmaf(tv, cN, -(tp * snN));
            float nxt = fmaf(gN, rot, (1.f - gN) * cdN);
            uint2 u; u.x = __float_as_uint(nxt); u.y = (unsigned)(s + 1);
            st_u64_agent(&stateTag[((size_t)((s + 1) & 1) * BNUM + b) * 512 + e], u);
            stb[(size_t)s * 512 + e] = nxt;           // for emit kernel
            lds8[e >> 6][e & 63] = nxt;               // own element, next step
            if (s == SLEN - 1) finalOut[b * 512 + e] = nxt;
            // prefetch next step's gates (wrap harmlessly at the end)
            int sp1 = (s + 1) & (SLEN - 1);
            gN  = pg [(size_t)sp1 * 512 + e];
            cdN = pcd[(size_t)sp1 * 512 + e];
            cN  = pc [(size_t)sp1 * 256 + (e >> 1)];
            snN = psn[(size_t)sp1 * 256 + (e >> 1)];
        } else if (s + 1 < SLEN) {
            // ---- poll peers' S_{s+1}[e] and fill LDS ----
            const uint2* p = stateTag +
                ((size_t)((s + 1) & 1) * BNUM + b) * 512 + e;
            uint2 u; int guard = 0;
            do { u = ld_u64_agent(p); }
            while (u.y != (unsigned)(s + 1) && ++guard < (1 << 16));
            lds8[e >> 6][e & 63] = __uint_as_float(u.x);
        }
        // barrier1 of next iteration orders all lds8 writes vs matvec reads.
    }
}

// ---------------------------------------------------------------------------
// Kernel C: emitted = og * (states @ Wo^T + bo). og staged in d_out by A.
// ---------------------------------------------------------------------------
__global__ __launch_bounds__(256) void emit_kernel(
    const float* __restrict__ states, const float* __restrict__ Wo,
    const float* __restrict__ bo, float* __restrict__ out)
{
    __shared__ float As[8][132];
    __shared__ float Bs[8][132];

    const int bn = blockIdx.x * 128;
    const int bm = blockIdx.y * 128;
    const int tid = threadIdx.x;
    const int tx = tid & 15, ty = tid >> 4;

    float acc[8][8];
    #pragma unroll
    for (int i = 0; i < 8; ++i)
        #pragma unroll
        for (int j = 0; j < 8; ++j) acc[i][j] = 0.f;

    for (int k0 = 0; k0 < DDIM; k0 += 8) {
        #pragma unroll
        for (int l = 0; l < 4; ++l) {
            int idx = l * 256 + tid;
            int kk = idx & 7, mm = idx >> 3;
            As[kk][mm] = states[(size_t)(bm + mm) * DDIM + k0 + kk];
            Bs[kk][mm] = Wo[(size_t)(bn + mm) * DDIM + k0 + kk];
        }
        __syncthreads();
        #pragma unroll
        for (int kk = 0; kk < 8; ++kk) {
            float av[8], bv[8];
            *(float4*)&av[0] = *(const float4*)&As[kk][ty * 8];
            *(float4*)&av[4] = *(const float4*)&As[kk][ty * 8 + 4];
            *(float4*)&bv[0] = *(const float4*)&Bs[kk][tx * 8];
            *(float4*)&bv[4] = *(const float4*)&Bs[kk][tx * 8 + 4];
            #pragma unroll
            for (int i = 0; i < 8; ++i)
                #pragma unroll
                for (int j = 0; j < 8; ++j)
                    acc[i][j] = fmaf(av[i], bv[j], acc[i][j]);
        }
        __syncthreads();
    }

    #pragma unroll
    for (int i = 0; i < 8; ++i) {
        int m = bm + ty * 8 + i;
        #pragma unroll
        for (int j = 0; j < 8; ++j) {
            int n = bn + tx * 8 + j;
            size_t idx = (size_t)m * 512 + n;
            float og = out[idx];
            out[idx] = og * (acc[i][j] + bo[n]);
        }
    }
}

// ---------------------------------------------------------------------------
extern "C" void kernel_launch(void* const* d_in, const int* in_sizes, int n_in,
                              void* d_out, int out_size, void* d_ws, size_t ws_size,
                              hipStream_t stream)
{
    const float* x  = (const float*)d_in[0];
    const float* Wu = (const float*)d_in[1];
    const float* bu = (const float*)d_in[2];
    const float* Wt = (const float*)d_in[3];
    const float* bt = (const float*)d_in[4];
    const float* Wa = (const float*)d_in[5];
    const float* ba = (const float*)d_in[6];
    const float* Wc = (const float*)d_in[7];
    const float* bc = (const float*)d_in[8];
    const float* Wg = (const float*)d_in[9];
    const float* bg = (const float*)d_in[10];
    const float* Wo = (const float*)d_in[11];
    const float* bo = (const float*)d_in[12];
    float* out = (float*)d_out;

    // workspace layout (floats)
    float* wsf    = (float*)d_ws;
    float* gbuf   = wsf;                               // 16384*512
    float* cosb   = gbuf   + (size_t)MTOT * 512;       // 16384*256
    float* sinb   = cosb   + (size_t)MTOT * 256;       // 16384*256
    float* cdbuf  = sinb   + (size_t)MTOT * 256;       // 16384*512
    float* states = cdbuf  + (size_t)MTOT * 512;       // 16384*512
    uint2* stateTag = (uint2*)(states + (size_t)MTOT * 512); // 2*8*512 uint2

    // clear tags through the sc1 path (same path the scan uses).
    clear_tags_kernel<<<16, 512, 0, stream>>>(stateTag);

    precompute_kernel<<<dim3(14, 128), 256, 0, stream>>>(
        x, Wu, bu, Wa, ba, Wc, bc, Wg, bg,
        gbuf, cosb, sinb, cdbuf, out /* og staged in emitted region */);

    scan_kernel<<<64, 512, 0, stream>>>(
        Wt, bt, gbuf, cosb, sinb, cdbuf,
        states, stateTag, out + (size_t)MTOT * 512);

    emit_kernel<<<dim3(4, 128), 256, 0, stream>>>(states, Wo, bo, out);
}